// Round 1
// baseline (371.187 us; speedup 1.0000x reference)
//
#include <hip/hip_runtime.h>
#include <math.h>

#define NUM_CLASSES 27
#define HDIM 256
#define WDIM 256
#define NPIX (HDIM * WDIM)

// Fixed problem shape: B=16, M=32, H=W=256.
#define NB_HIST 512              // B*M blocks, one per (b,m)
#define NB_BND 512               // B*HDIM/8 blocks, 8 rows each
#define NB_TOTAL (NB_HIST + NB_BND)
#define ROWS_PER_BND_BLOCK 8

// ws layout (floats), all slots written every launch (no zeroing needed):
//   ws[0    .. 512)  : entropy per (b,m) block
//   ws[512  .. 1024) : intersection per boundary block
//   ws[1024 .. 1536) : union per boundary block
//   ws[1536 .. 2048) : dbc-term sum per boundary block

// Completion counter for single-kernel finalize (last block reduces ws).
// Invariant: 0 at kernel entry; the finalizing block resets it to 0, so
// graph replays and rocprof counter-replays both see a clean counter.
__device__ unsigned int g_done_count = 0u;

__global__ __launch_bounds__(512) void fused_kernel(
    const float* __restrict__ masks, const int* __restrict__ sem,
    const float* __restrict__ depth, float* __restrict__ ws,
    float* __restrict__ out, int M, int B) {
  // Conflict-free layout: bin c of thread t at s_hist[c][t].
  // Row stride = 512 floats (== 0 mod 32 banks), so bank = t & 31:
  // class-independent, exactly 2 lanes/bank per wave access -> free (m136).
  __shared__ float s_hist[28][512];  // 57 KB
  __shared__ float s_part[16][32];
  __shared__ float s_i[8], s_u[8], s_t[8];
  __shared__ unsigned int s_last;

  const int tid = threadIdx.x;

  if (blockIdx.x < NB_HIST) {
    // ---------------- histogram + entropy for one (b,m) ----------------
    const int bm = blockIdx.x;
    const int b = bm / M;
    const int m = bm % M;

    float* col = &s_hist[0][tid];  // bin c at col[c*512]
#pragma unroll
    for (int c = 0; c < 28; ++c) col[c * 512] = 0.0f;
    // no sync needed: hot loop touches only this thread's own column

    const float4* __restrict__ m4 =
        (const float4*)(masks + ((size_t)b * M + m) * (size_t)NPIX);
    const int4* __restrict__ s4 = (const int4*)(sem + (size_t)b * (size_t)NPIX);

    const int iters = NPIX / 4 / 512;  // 32
#pragma unroll 4
    for (int it = 0; it < iters; ++it) {
      const int idx = it * 512 + tid;
      const float4 mv = m4[idx];
      const int4 cv = s4[idx];
      // ds_add_f32 (no return): single DS op per update, no read->add->write
      // latency chain, no lgkmcnt stall. Each column is owned by exactly one
      // thread and DS ops are in-order per wave, so the addition order (and
      // hence the float result) is bit-identical to the += version.
      atomicAdd(&col[cv.x * 512], mv.x);
      atomicAdd(&col[cv.y * 512], mv.y);
      atomicAdd(&col[cv.z * 512], mv.z);
      atomicAdd(&col[cv.w * 512], mv.w);
    }
    __syncthreads();

    // stage 2: thread (c = tid&31, s = tid>>5) sums bin c over 32 columns.
    // Skew iteration by c so banks stay spread (2-way only).
    {
      const int c = tid & 31;
      const int s = tid >> 5;
      if (c < 28) {
        float acc = 0.f;
#pragma unroll
        for (int i = 0; i < 32; ++i)
          acc += s_hist[c][s * 32 + ((i + c) & 31)];
        s_part[s][c] = acc;
      }
    }
    __syncthreads();

    // stage 3: one wave finishes
    if (tid < 64) {
      float tot = 0.f;
      if (tid < 28) {
#pragma unroll
        for (int g = 0; g < 16; ++g) tot += s_part[g][tid];
      }
      float ms = tot;  // sum of all bins == sum over n of mask
      for (int off = 32; off > 0; off >>= 1) ms += __shfl_xor(ms, off);
      ms += 1e-6f;
      float ent = 0.f;
      if (tid < NUM_CLASSES) {
        float p = fminf(fmaxf(tot / ms, 1e-7f), 1.0f);
        if (p > 1e-6f) ent = p * logf(p + 1e-10f);
      }
      for (int off = 32; off > 0; off >>= 1) ent += __shfl_xor(ent, off);
      if (tid == 0)
        __hip_atomic_store(&ws[bm], -ent, __ATOMIC_RELAXED,
                           __HIP_MEMORY_SCOPE_AGENT);
    }
  } else {
    // ---------------- boundary IoU + depth coherence: 8 rows/block ----------------
    const int j = blockIdx.x - NB_HIST;
    const int wave = tid >> 6;
    const int lane = tid & 63;
    const int brow = j * ROWS_PER_BND_BLOCK + wave;  // all 8 rows share b
    const int b = brow >> 8;
    const int y = brow & 255;

    const size_t rowoff = (size_t)b * NPIX + (size_t)y * WDIM;
    const float4* mp = (const float4*)(masks + (size_t)b * M * NPIX + (size_t)y * WDIM);
    const float4* dp = (const float4*)(depth + rowoff);
    const int4* sp = (const int4*)(sem + rowoff);

    const int uoff = (y > 0) ? -(WDIM / 4) : 0;

    const float4 mv = mp[lane];
    const float4 mvu = mp[lane + uoff];
    const float4 dv = dp[lane];
    const float4 dvu = dp[lane + uoff];
    const int4 sv = sp[lane];
    const int4 svu = sp[lane + uoff];

    const int src = (lane > 0) ? (lane - 1) : 0;
    float mw = __shfl(mv.w, src);
    float dw = __shfl(dv.w, src);
    int swv = __shfl(sv.w, src);
    if (lane == 0) { mw = mv.x; dw = dv.x; swv = sv.x; }

    const float ml[4] = {mw, mv.x, mv.y, mv.z};
    const float dl[4] = {dw, dv.x, dv.y, dv.z};
    const int sl[4] = {swv, sv.x, sv.y, sv.z};
    const float mc[4] = {mv.x, mv.y, mv.z, mv.w};
    const float dc[4] = {dv.x, dv.y, dv.z, dv.w};
    const int sc[4] = {sv.x, sv.y, sv.z, sv.w};
    const float mu[4] = {mvu.x, mvu.y, mvu.z, mvu.w};
    const float du[4] = {dvu.x, dvu.y, dvu.z, dvu.w};
    const int su[4] = {svu.x, svu.y, svu.z, svu.w};

    float inter = 0.f, uni = 0.f, term = 0.f;
#pragma unroll
    for (int k = 0; k < 4; ++k) {
      const bool semb = (sc[k] != sl[k]) || (sc[k] != su[k]);
      const bool instb = (fabsf(mc[k] - ml[k]) > 0.3f) || (fabsf(mc[k] - mu[k]) > 0.3f);
      inter += (semb && instb) ? 1.0f : 0.0f;
      uni += (semb || instb) ? 1.0f : 0.0f;
      const float gx = dc[k] - dl[k];
      const float gy = dc[k] - du[k];
      const float db = sqrtf(fmaxf(gx * gx + gy * gy, 1e-24f));
      const float dbc = fminf(db, 2.0f);
      term += semb ? 0.0f : (1.0f + 3.0f * dbc) * dbc;
    }

    for (int off = 32; off > 0; off >>= 1) {
      inter += __shfl_down(inter, off);
      uni += __shfl_down(uni, off);
      term += __shfl_down(term, off);
    }
    if (lane == 0) { s_i[wave] = inter; s_u[wave] = uni; s_t[wave] = term; }
    __syncthreads();
    if (tid == 0) {
      float bi = 0.f, bu = 0.f, bt = 0.f;
#pragma unroll
      for (int w = 0; w < 8; ++w) { bi += s_i[w]; bu += s_u[w]; bt += s_t[w]; }
      __hip_atomic_store(&ws[512 + j], bi, __ATOMIC_RELAXED,
                         __HIP_MEMORY_SCOPE_AGENT);
      __hip_atomic_store(&ws[1024 + j], bu, __ATOMIC_RELAXED,
                         __HIP_MEMORY_SCOPE_AGENT);
      __hip_atomic_store(&ws[1536 + j], bt, __ATOMIC_RELAXED,
                         __HIP_MEMORY_SCOPE_AGENT);
    }
  }

  // ---------------- last-block finalize (replaces the second kernel) ----------------
  // All ws writes above are by tid 0 of each block with agent-scope stores;
  // the release fetch_add below orders them device-wide (G16: device-scope
  // atomics across non-coherent XCD L2s). The finalizing block reads ws with
  // agent-scope loads so it cannot hit a stale line left in its XCD's L2 by a
  // previous graph replay.
  __syncthreads();
  if (tid == 0) {
    __threadfence();  // belt & suspenders: flush this block's writes
    const unsigned int prev = __hip_atomic_fetch_add(
        &g_done_count, 1u, __ATOMIC_ACQ_REL, __HIP_MEMORY_SCOPE_AGENT);
    s_last = (prev == NB_TOTAL - 1u) ? 1u : 0u;
  }
  __syncthreads();

  if (s_last != 0u) {
    const int lane = tid & 63;
    const int wave = tid >> 6;

    float e = __hip_atomic_load(&ws[tid], __ATOMIC_RELAXED,
                                __HIP_MEMORY_SCOPE_AGENT);
    float dbc = __hip_atomic_load(&ws[1536 + tid], __ATOMIC_RELAXED,
                                  __HIP_MEMORY_SCOPE_AGENT);
    float inter = __hip_atomic_load(&ws[512 + tid], __ATOMIC_RELAXED,
                                    __HIP_MEMORY_SCOPE_AGENT);
    float uni = __hip_atomic_load(&ws[1024 + tid], __ATOMIC_RELAXED,
                                  __HIP_MEMORY_SCOPE_AGENT);

    // per-b IoU: boundary blocks of image b are tid in [32b, 32b+32)
    for (int off = 16; off > 0; off >>= 1) {
      inter += __shfl_down(inter, off, 32);
      uni += __shfl_down(uni, off, 32);
    }
    if ((tid & 31) == 0) s_part[2][tid >> 5] = inter / (uni + 1e-8f);

    for (int off = 32; off > 0; off >>= 1) {
      e += __shfl_down(e, off);
      dbc += __shfl_down(dbc, off);
    }
    if (lane == 0) { s_part[0][wave] = e; s_part[1][wave] = dbc; }
    __syncthreads();

    if (tid == 0) {
      float se = 0.f, sd = 0.f, sr = 0.f;
#pragma unroll
      for (int w = 0; w < 8; ++w) { se += s_part[0][w]; sd += s_part[1][w]; }
#pragma unroll
      for (int b2 = 0; b2 < 16; ++b2) sr += s_part[2][b2];
      const float l_u = se / ((float)(B * M) + 1e-8f);
      const float l_b = 1.0f - sr / (float)B;
      const float l_d = sd / (float)((size_t)B * NPIX);
      out[0] = l_u;
      out[1] = l_b;
      out[2] = l_d;
      out[3] = 0.3f * l_u + 0.2f * l_b + 0.2f * l_d;
      // restore invariant for the next launch / graph replay
      __hip_atomic_store(&g_done_count, 0u, __ATOMIC_RELAXED,
                         __HIP_MEMORY_SCOPE_AGENT);
    }
  }
}

extern "C" void kernel_launch(void* const* d_in, const int* in_sizes, int n_in,
                              void* d_out, int out_size, void* d_ws, size_t ws_size,
                              hipStream_t stream) {
  const int* sem = (const int*)d_in[0];        // (B, N) int32
  const float* masks = (const float*)d_in[1];  // (B, M, N) f32
  const float* depth = (const float*)d_in[2];  // (B, N) f32

  const int B = in_sizes[0] / NPIX;         // 16
  const int M = in_sizes[1] / in_sizes[0];  // 32
  float* ws = (float*)d_ws;
  float* out = (float*)d_out;

  fused_kernel<<<NB_TOTAL, 512, 0, stream>>>(masks, sem, depth, ws, out, M, B);
}

// Round 2
// 243.781 us; speedup vs baseline: 1.5226x; 1.5226x over previous
//
#include <hip/hip_runtime.h>
#include <math.h>

#define NUM_CLASSES 27
#define HDIM 256
#define WDIM 256
#define NPIX (HDIM * WDIM)

// Fixed problem shape: B=16, M=32, H=W=256.
#define NB_HIST 512              // B*M blocks, one per (b,m)
#define NB_BND 512               // B*HDIM/8 blocks, 8 rows each
#define NB_TOTAL (NB_HIST + NB_BND)
#define ROWS_PER_BND_BLOCK 8

// ws layout (floats), all slots written every launch (no zeroing needed):
//   ws[0    .. 512)  : entropy per (b,m) block
//   ws[512  .. 1024) : intersection per boundary block
//   ws[1024 .. 1536) : union per boundary block
//   ws[1536 .. 2048) : dbc-term sum per boundary block

// Completion counter for single-kernel finalize (last block reduces ws).
// Invariant: 0 at kernel entry; the finalizing block resets it to 0, so
// graph replays and rocprof counter-replays both see a clean counter.
__device__ unsigned int g_done_count = 0u;

__global__ __launch_bounds__(512) void fused_kernel(
    const float* __restrict__ masks, const int* __restrict__ sem,
    const float* __restrict__ depth, float* __restrict__ ws,
    float* __restrict__ out, int M, int B) {
  // Conflict-free layout: bin c of thread t at s_hist[c][t].
  // Row stride = 512 floats (== 0 mod 32 banks), so bank = t & 31:
  // class-independent, exactly 2 lanes/bank per wave access -> free (m136).
  __shared__ float s_hist[28][512];  // 57 KB
  __shared__ float s_part[16][32];
  __shared__ float s_i[8], s_u[8], s_t[8];
  __shared__ unsigned int s_last;

  const int tid = threadIdx.x;

  if (blockIdx.x < NB_HIST) {
    // ---------------- histogram + entropy for one (b,m) ----------------
    const int bm = blockIdx.x;
    const int b = bm / M;
    const int m = bm % M;

    float* col = &s_hist[0][tid];  // bin c at col[c*512]
#pragma unroll
    for (int c = 0; c < 28; ++c) col[c * 512] = 0.0f;
    // no sync needed: hot loop touches only this thread's own column

    const float4* __restrict__ m4 =
        (const float4*)(masks + ((size_t)b * M + m) * (size_t)NPIX);
    const int4* __restrict__ s4 = (const int4*)(sem + (size_t)b * (size_t)NPIX);

    const int iters = NPIX / 4 / 512;  // 32
    // NOTE (R1 post-mortem): atomicAdd on this LDS column was a 3x kernel
    // regression (flat-atomic path, VALUBusy 1.8%). Plain += (ds_read/ds_write)
    // is the measured-good form — do not "optimize" it back to atomics.
#pragma unroll 4
    for (int it = 0; it < iters; ++it) {
      const int idx = it * 512 + tid;
      const float4 mv = m4[idx];
      const int4 cv = s4[idx];
      col[cv.x * 512] += mv.x;
      col[cv.y * 512] += mv.y;
      col[cv.z * 512] += mv.z;
      col[cv.w * 512] += mv.w;
    }
    __syncthreads();

    // stage 2: thread (c = tid&31, s = tid>>5) sums bin c over 32 columns.
    // Skew iteration by c so banks stay spread (2-way only).
    {
      const int c = tid & 31;
      const int s = tid >> 5;
      if (c < 28) {
        float acc = 0.f;
#pragma unroll
        for (int i = 0; i < 32; ++i)
          acc += s_hist[c][s * 32 + ((i + c) & 31)];
        s_part[s][c] = acc;
      }
    }
    __syncthreads();

    // stage 3: one wave finishes
    if (tid < 64) {
      float tot = 0.f;
      if (tid < 28) {
#pragma unroll
        for (int g = 0; g < 16; ++g) tot += s_part[g][tid];
      }
      float ms = tot;  // sum of all bins == sum over n of mask
      for (int off = 32; off > 0; off >>= 1) ms += __shfl_xor(ms, off);
      ms += 1e-6f;
      float ent = 0.f;
      if (tid < NUM_CLASSES) {
        float p = fminf(fmaxf(tot / ms, 1e-7f), 1.0f);
        if (p > 1e-6f) ent = p * logf(p + 1e-10f);
      }
      for (int off = 32; off > 0; off >>= 1) ent += __shfl_xor(ent, off);
      if (tid == 0)
        __hip_atomic_store(&ws[bm], -ent, __ATOMIC_RELAXED,
                           __HIP_MEMORY_SCOPE_AGENT);
    }
  } else {
    // ---------------- boundary IoU + depth coherence: 8 rows/block ----------------
    const int j = blockIdx.x - NB_HIST;
    const int wave = tid >> 6;
    const int lane = tid & 63;
    const int brow = j * ROWS_PER_BND_BLOCK + wave;  // all 8 rows share b
    const int b = brow >> 8;
    const int y = brow & 255;

    const size_t rowoff = (size_t)b * NPIX + (size_t)y * WDIM;
    const float4* mp = (const float4*)(masks + (size_t)b * M * NPIX + (size_t)y * WDIM);
    const float4* dp = (const float4*)(depth + rowoff);
    const int4* sp = (const int4*)(sem + rowoff);

    const int uoff = (y > 0) ? -(WDIM / 4) : 0;

    const float4 mv = mp[lane];
    const float4 mvu = mp[lane + uoff];
    const float4 dv = dp[lane];
    const float4 dvu = dp[lane + uoff];
    const int4 sv = sp[lane];
    const int4 svu = sp[lane + uoff];

    const int src = (lane > 0) ? (lane - 1) : 0;
    float mw = __shfl(mv.w, src);
    float dw = __shfl(dv.w, src);
    int swv = __shfl(sv.w, src);
    if (lane == 0) { mw = mv.x; dw = dv.x; swv = sv.x; }

    const float ml[4] = {mw, mv.x, mv.y, mv.z};
    const float dl[4] = {dw, dv.x, dv.y, dv.z};
    const int sl[4] = {swv, sv.x, sv.y, sv.z};
    const float mc[4] = {mv.x, mv.y, mv.z, mv.w};
    const float dc[4] = {dv.x, dv.y, dv.z, dv.w};
    const int sc[4] = {sv.x, sv.y, sv.z, sv.w};
    const float mu[4] = {mvu.x, mvu.y, mvu.z, mvu.w};
    const float du[4] = {dvu.x, dvu.y, dvu.z, dvu.w};
    const int su[4] = {svu.x, svu.y, svu.z, svu.w};

    float inter = 0.f, uni = 0.f, term = 0.f;
#pragma unroll
    for (int k = 0; k < 4; ++k) {
      const bool semb = (sc[k] != sl[k]) || (sc[k] != su[k]);
      const bool instb = (fabsf(mc[k] - ml[k]) > 0.3f) || (fabsf(mc[k] - mu[k]) > 0.3f);
      inter += (semb && instb) ? 1.0f : 0.0f;
      uni += (semb || instb) ? 1.0f : 0.0f;
      const float gx = dc[k] - dl[k];
      const float gy = dc[k] - du[k];
      const float db = sqrtf(fmaxf(gx * gx + gy * gy, 1e-24f));
      const float dbc = fminf(db, 2.0f);
      term += semb ? 0.0f : (1.0f + 3.0f * dbc) * dbc;
    }

    for (int off = 32; off > 0; off >>= 1) {
      inter += __shfl_down(inter, off);
      uni += __shfl_down(uni, off);
      term += __shfl_down(term, off);
    }
    if (lane == 0) { s_i[wave] = inter; s_u[wave] = uni; s_t[wave] = term; }
    __syncthreads();
    if (tid == 0) {
      float bi = 0.f, bu = 0.f, bt = 0.f;
#pragma unroll
      for (int w = 0; w < 8; ++w) { bi += s_i[w]; bu += s_u[w]; bt += s_t[w]; }
      __hip_atomic_store(&ws[512 + j], bi, __ATOMIC_RELAXED,
                         __HIP_MEMORY_SCOPE_AGENT);
      __hip_atomic_store(&ws[1024 + j], bu, __ATOMIC_RELAXED,
                         __HIP_MEMORY_SCOPE_AGENT);
      __hip_atomic_store(&ws[1536 + j], bt, __ATOMIC_RELAXED,
                         __HIP_MEMORY_SCOPE_AGENT);
    }
  }

  // ---------------- last-block finalize (replaces the second kernel) ----------------
  // All ws writes above are agent-scope atomic stores by tid 0 of each block;
  // the ACQ_REL fetch_add below is the release that publishes them device-wide
  // (G16: device-scope atomics across non-coherent XCD L2s) and the acquire
  // that lets the finalizing block read them. No explicit __threadfence —
  // the scoped atomic already emits the required cache ops, and an extra
  // fence per block is a per-block L2 writeback we don't need.
  __syncthreads();
  if (tid == 0) {
    const unsigned int prev = __hip_atomic_fetch_add(
        &g_done_count, 1u, __ATOMIC_ACQ_REL, __HIP_MEMORY_SCOPE_AGENT);
    s_last = (prev == NB_TOTAL - 1u) ? 1u : 0u;
  }
  __syncthreads();

  if (s_last != 0u) {
    const int lane = tid & 63;
    const int wave = tid >> 6;

    float e = __hip_atomic_load(&ws[tid], __ATOMIC_RELAXED,
                                __HIP_MEMORY_SCOPE_AGENT);
    float dbc = __hip_atomic_load(&ws[1536 + tid], __ATOMIC_RELAXED,
                                  __HIP_MEMORY_SCOPE_AGENT);
    float inter = __hip_atomic_load(&ws[512 + tid], __ATOMIC_RELAXED,
                                    __HIP_MEMORY_SCOPE_AGENT);
    float uni = __hip_atomic_load(&ws[1024 + tid], __ATOMIC_RELAXED,
                                  __HIP_MEMORY_SCOPE_AGENT);

    // per-b IoU: boundary blocks of image b are tid in [32b, 32b+32)
    for (int off = 16; off > 0; off >>= 1) {
      inter += __shfl_down(inter, off, 32);
      uni += __shfl_down(uni, off, 32);
    }
    if ((tid & 31) == 0) s_part[2][tid >> 5] = inter / (uni + 1e-8f);

    for (int off = 32; off > 0; off >>= 1) {
      e += __shfl_down(e, off);
      dbc += __shfl_down(dbc, off);
    }
    if (lane == 0) { s_part[0][wave] = e; s_part[1][wave] = dbc; }
    __syncthreads();

    if (tid == 0) {
      float se = 0.f, sd = 0.f, sr = 0.f;
#pragma unroll
      for (int w = 0; w < 8; ++w) { se += s_part[0][w]; sd += s_part[1][w]; }
#pragma unroll
      for (int b2 = 0; b2 < 16; ++b2) sr += s_part[2][b2];
      const float l_u = se / ((float)(B * M) + 1e-8f);
      const float l_b = 1.0f - sr / (float)B;
      const float l_d = sd / (float)((size_t)B * NPIX);
      out[0] = l_u;
      out[1] = l_b;
      out[2] = l_d;
      out[3] = 0.3f * l_u + 0.2f * l_b + 0.2f * l_d;
      // restore invariant for the next launch / graph replay
      __hip_atomic_store(&g_done_count, 0u, __ATOMIC_RELAXED,
                         __HIP_MEMORY_SCOPE_AGENT);
    }
  }
}

extern "C" void kernel_launch(void* const* d_in, const int* in_sizes, int n_in,
                              void* d_out, int out_size, void* d_ws, size_t ws_size,
                              hipStream_t stream) {
  const int* sem = (const int*)d_in[0];        // (B, N) int32
  const float* masks = (const float*)d_in[1];  // (B, M, N) f32
  const float* depth = (const float*)d_in[2];  // (B, N) f32

  const int B = in_sizes[0] / NPIX;         // 16
  const int M = in_sizes[1] / in_sizes[0];  // 32
  float* ws = (float*)d_ws;
  float* out = (float*)d_out;

  fused_kernel<<<NB_TOTAL, 512, 0, stream>>>(masks, sem, depth, ws, out, M, B);
}

// Round 3
// 202.369 us; speedup vs baseline: 1.8342x; 1.2046x over previous
//
#include <hip/hip_runtime.h>
#include <math.h>

#define NUM_CLASSES 27
#define HDIM 256
#define WDIM 256
#define NPIX (HDIM * WDIM)

// Fixed problem shape: B=16, M=32, H=W=256.
// 256-thread blocks: hist LDS = 28*256*4 = 28.7 KB -> ~5 blocks/CU (20 waves/CU)
// vs the old 512-thread/57KB form (2 blocks/CU, 16 waves/CU, VALUBusy ~5%).
#define NB_HIST 512              // B*M blocks, one per (b,m)
#define NB_BND 1024              // B*HDIM/4 blocks, 4 rows each (1 row/wave)
#define ROWS_PER_BND_BLOCK 4

// ws layout (floats), all slots written every launch (no zeroing needed):
//   ws[0    .. 512)  : entropy per (b,m) block
//   ws[512  .. 1536) : intersection per boundary block (1024)
//   ws[1536 .. 2560) : union per boundary block (1024)
//   ws[2560 .. 3584) : dbc-term sum per boundary block (1024)
//
// R1/R2 post-mortems (do not regress):
//  - atomicAdd on LDS histogram -> flat-atomic path, 3x kernel regression.
//  - single-kernel finalize via per-block agent-scope ACQ_REL fetch_add ->
//    per-block L2 writeback/invalidate, 2.5x kernel regression. Two-kernel
//    form relies on the (free) kernel-boundary release/acquire instead.

__global__ __launch_bounds__(256) void fused_kernel(
    const float* __restrict__ masks, const int* __restrict__ sem,
    const float* __restrict__ depth, float* __restrict__ ws, int M) {
  // Conflict-free layout: bin c of thread t at s_hist[c][t].
  // Row stride = 256 floats (== 0 mod 32 banks), so bank = t & 31:
  // class-independent, exactly 2 lanes/bank per wave access -> free (m136).
  __shared__ float s_hist[28][256];  // 28.7 KB
  __shared__ float s_part[8][32];
  __shared__ float s_i[4], s_u[4], s_t[4];

  const int tid = threadIdx.x;

  if (blockIdx.x < NB_HIST) {
    // ---------------- histogram + entropy for one (b,m) ----------------
    const int bm = blockIdx.x;
    const int b = bm / M;
    const int m = bm % M;

    float* col = &s_hist[0][tid];  // bin c at col[c*256]
#pragma unroll
    for (int c = 0; c < 28; ++c) col[c * 256] = 0.0f;
    // no sync needed: hot loop touches only this thread's own column

    const float4* __restrict__ m4 =
        (const float4*)(masks + ((size_t)b * M + m) * (size_t)NPIX);
    const int4* __restrict__ s4 = (const int4*)(sem + (size_t)b * (size_t)NPIX);

    const int iters = NPIX / 4 / 256;  // 64
#pragma unroll 4
    for (int it = 0; it < iters; ++it) {
      const int idx = it * 256 + tid;
      const float4 mv = m4[idx];
      const int4 cv = s4[idx];
      col[cv.x * 256] += mv.x;
      col[cv.y * 256] += mv.y;
      col[cv.z * 256] += mv.z;
      col[cv.w * 256] += mv.w;
    }
    __syncthreads();

    // stage 2: thread (c = tid&31, s = tid>>5) sums bin c over 32 columns.
    // Skew iteration by c so banks stay spread (2-way only).
    {
      const int c = tid & 31;
      const int s = tid >> 5;  // 8 groups of 32 columns
      if (c < 28) {
        float acc = 0.f;
#pragma unroll
        for (int i = 0; i < 32; ++i)
          acc += s_hist[c][s * 32 + ((i + c) & 31)];
        s_part[s][c] = acc;
      }
    }
    __syncthreads();

    // stage 3: one wave finishes
    if (tid < 64) {
      float tot = 0.f;
      if (tid < 28) {
#pragma unroll
        for (int g = 0; g < 8; ++g) tot += s_part[g][tid];
      }
      float ms = tot;  // sum of all bins == sum over n of mask
      for (int off = 32; off > 0; off >>= 1) ms += __shfl_xor(ms, off);
      ms += 1e-6f;
      float ent = 0.f;
      if (tid < NUM_CLASSES) {
        float p = fminf(fmaxf(tot / ms, 1e-7f), 1.0f);
        if (p > 1e-6f) ent = p * logf(p + 1e-10f);
      }
      for (int off = 32; off > 0; off >>= 1) ent += __shfl_xor(ent, off);
      if (tid == 0) ws[bm] = -ent;
    }
  } else {
    // ---------------- boundary IoU + depth coherence: 4 rows/block ----------------
    const int j = blockIdx.x - NB_HIST;
    const int wave = tid >> 6;
    const int lane = tid & 63;
    const int brow = j * ROWS_PER_BND_BLOCK + wave;  // all 4 rows share b
    const int b = brow >> 8;
    const int y = brow & 255;

    const size_t rowoff = (size_t)b * NPIX + (size_t)y * WDIM;
    const float4* mp = (const float4*)(masks + (size_t)b * M * NPIX + (size_t)y * WDIM);
    const float4* dp = (const float4*)(depth + rowoff);
    const int4* sp = (const int4*)(sem + rowoff);

    const int uoff = (y > 0) ? -(WDIM / 4) : 0;

    const float4 mv = mp[lane];
    const float4 mvu = mp[lane + uoff];
    const float4 dv = dp[lane];
    const float4 dvu = dp[lane + uoff];
    const int4 sv = sp[lane];
    const int4 svu = sp[lane + uoff];

    const int src = (lane > 0) ? (lane - 1) : 0;
    float mw = __shfl(mv.w, src);
    float dw = __shfl(dv.w, src);
    int swv = __shfl(sv.w, src);
    if (lane == 0) { mw = mv.x; dw = dv.x; swv = sv.x; }

    const float ml[4] = {mw, mv.x, mv.y, mv.z};
    const float dl[4] = {dw, dv.x, dv.y, dv.z};
    const int sl[4] = {swv, sv.x, sv.y, sv.z};
    const float mc[4] = {mv.x, mv.y, mv.z, mv.w};
    const float dc[4] = {dv.x, dv.y, dv.z, dv.w};
    const int sc[4] = {sv.x, sv.y, sv.z, sv.w};
    const float mu[4] = {mvu.x, mvu.y, mvu.z, mvu.w};
    const float du[4] = {dvu.x, dvu.y, dvu.z, dvu.w};
    const int su[4] = {svu.x, svu.y, svu.z, svu.w};

    float inter = 0.f, uni = 0.f, term = 0.f;
#pragma unroll
    for (int k = 0; k < 4; ++k) {
      const bool semb = (sc[k] != sl[k]) || (sc[k] != su[k]);
      const bool instb = (fabsf(mc[k] - ml[k]) > 0.3f) || (fabsf(mc[k] - mu[k]) > 0.3f);
      inter += (semb && instb) ? 1.0f : 0.0f;
      uni += (semb || instb) ? 1.0f : 0.0f;
      const float gx = dc[k] - dl[k];
      const float gy = dc[k] - du[k];
      const float db = sqrtf(fmaxf(gx * gx + gy * gy, 1e-24f));
      const float dbc = fminf(db, 2.0f);
      term += semb ? 0.0f : (1.0f + 3.0f * dbc) * dbc;
    }

    for (int off = 32; off > 0; off >>= 1) {
      inter += __shfl_down(inter, off);
      uni += __shfl_down(uni, off);
      term += __shfl_down(term, off);
    }
    if (lane == 0) { s_i[wave] = inter; s_u[wave] = uni; s_t[wave] = term; }
    __syncthreads();
    if (tid == 0) {
      float bi = 0.f, bu = 0.f, bt = 0.f;
#pragma unroll
      for (int w = 0; w < 4; ++w) { bi += s_i[w]; bu += s_u[w]; bt += s_t[w]; }
      ws[512 + j] = bi;
      ws[1536 + j] = bu;
      ws[2560 + j] = bt;
    }
  }
}

// ---------------- finalize: reduce all per-block partials ----------------
__global__ __launch_bounds__(512) void finalize_kernel(
    const float* __restrict__ ws, float* __restrict__ out, int B, int M) {
  const int tid = threadIdx.x;
  const int lane = tid & 63;
  const int wave = tid >> 6;
  __shared__ float s_e[8], s_d[8], s_r[16];

  float e = ws[tid];  // entropy partials (512)
  // boundary partials: 1024 each; thread tid takes pair (2*tid, 2*tid+1).
  // Pair shares the same image b: b = j/64 = tid/32, so threads
  // [32b, 32b+32) cover exactly image b's 64 boundary blocks.
  float inter = ws[512 + 2 * tid] + ws[512 + 2 * tid + 1];
  float uni = ws[1536 + 2 * tid] + ws[1536 + 2 * tid + 1];
  float dbc = ws[2560 + 2 * tid] + ws[2560 + 2 * tid + 1];

  for (int off = 16; off > 0; off >>= 1) {
    inter += __shfl_down(inter, off, 32);
    uni += __shfl_down(uni, off, 32);
  }
  if ((tid & 31) == 0) s_r[tid >> 5] = inter / (uni + 1e-8f);

  for (int off = 32; off > 0; off >>= 1) {
    e += __shfl_down(e, off);
    dbc += __shfl_down(dbc, off);
  }
  if (lane == 0) { s_e[wave] = e; s_d[wave] = dbc; }
  __syncthreads();

  if (tid == 0) {
    float se = 0.f, sd = 0.f, sr = 0.f;
#pragma unroll
    for (int w = 0; w < 8; ++w) { se += s_e[w]; sd += s_d[w]; }
#pragma unroll
    for (int b = 0; b < 16; ++b) sr += s_r[b];
    const float l_u = se / ((float)(B * M) + 1e-8f);
    const float l_b = 1.0f - sr / (float)B;
    const float l_d = sd / (float)((size_t)B * NPIX);
    out[0] = l_u;
    out[1] = l_b;
    out[2] = l_d;
    out[3] = 0.3f * l_u + 0.2f * l_b + 0.2f * l_d;
  }
}

extern "C" void kernel_launch(void* const* d_in, const int* in_sizes, int n_in,
                              void* d_out, int out_size, void* d_ws, size_t ws_size,
                              hipStream_t stream) {
  const int* sem = (const int*)d_in[0];        // (B, N) int32
  const float* masks = (const float*)d_in[1];  // (B, M, N) f32
  const float* depth = (const float*)d_in[2];  // (B, N) f32

  const int B = in_sizes[0] / NPIX;         // 16
  const int M = in_sizes[1] / in_sizes[0];  // 32
  float* ws = (float*)d_ws;
  float* out = (float*)d_out;

  fused_kernel<<<NB_HIST + NB_BND, 256, 0, stream>>>(masks, sem, depth, ws, M);
  finalize_kernel<<<1, 512, 0, stream>>>(ws, out, B, M);
}